// Round 19
// baseline (141.332 us; speedup 1.0000x reference)
//
#include <hip/hip_runtime.h>
#include <math.h>

// Problem constants (from reference)
constexpr int B_  = 16;
constexpr int LQ_ = 1024;
constexpr int LK_ = 4096;
constexpr int D_  = 256;
constexpr float HALF_BW_F = 64.0f;         // 128 // 2
constexpr float SCALE = 0.0625f;           // (D^-0.25)^2 = 1/sqrt(256)

typedef short  bf16x8 __attribute__((ext_vector_type(8)));
typedef float  f32x4v __attribute__((ext_vector_type(4)));

constexpr int ROWS_PER_WAVE = 16;          // one MFMA M-tile per wave-block
constexpr int NUNIT = (B_ * LQ_) / ROWS_PER_WAVE;  // 1024 single-wave blocks
constexpr int NXCD  = 8;
constexpr int UNIT_PER_XCD = NUNIT / NXCD; // 128
constexpr int KSPAN = 192;                 // wave key span <= 15*4+129 = 189
constexpr int NT    = 12;                  // key tiles of 16

__device__ __forceinline__ unsigned short f2bf(float f) {
    unsigned int u = __float_as_uint(f);
    return (unsigned short)((u + 0x7FFFu + ((u >> 16) & 1u)) >> 16);  // RNE
}
__device__ __forceinline__ bf16x8 pack8(float4 a, float4 b) {
    bf16x8 r;
    r[0] = (short)f2bf(a.x); r[1] = (short)f2bf(a.y);
    r[2] = (short)f2bf(a.z); r[3] = (short)f2bf(a.w);
    r[4] = (short)f2bf(b.x); r[5] = (short)f2bf(b.y);
    r[6] = (short)f2bf(b.z); r[7] = (short)f2bf(b.w);
    return r;
}
__device__ __forceinline__ float grp16_max(float v) {
    #pragma unroll
    for (int off = 8; off > 0; off >>= 1)
        v = fmaxf(v, __shfl_xor(v, off, 64));
    return v;
}
__device__ __forceinline__ float grp16_sum(float v) {
    #pragma unroll
    for (int off = 8; off > 0; off >>= 1)
        v += __shfl_xor(v, off, 64);
    return v;
}

// Decomposition round: zeros via hipMemsetAsync (7.0 TB/s proven by the
// harness's own fillBuffer), V via hipMemcpyAsync D2D (~25us, R1), leaving
// this kernel = MFMA scores + band-stripe stores ONLY (~105MB read,
// ~24MB write). 1024 single-wave blocks (16 q-rows each) for max
// scheduling freedom. dur_us - 60us tells us the true cost of the score
// phase, which 9 falsified micro-theories never isolated.
__global__ __launch_bounds__(64, 2) void score_kernel(
    const float* __restrict__ Q, const float* __restrict__ K,
    const int* __restrict__ qlen, const int* __restrict__ klen,
    float* __restrict__ Wout)
{
    const int Bid  = blockIdx.x;
    // XCD swizzle: each XCD owns 128 consecutive units (2048 rows = 2 batches)
    const int rb   = (Bid & (NXCD - 1)) * UNIT_PER_XCD + (Bid >> 3);
    const int lane = threadIdx.x;          // single wave per block
    const int row0 = rb * ROWS_PER_WAVE;
    const int b    = row0 >> 10;
    const int qi0  = row0 & (LQ_ - 1);

    __shared__ float s_sc[ROWS_PER_WAVE][KSPAN];   // 12 KB

    const int   key_len = klen[b];
    const float slope   = (float)key_len / (float)qlen[b];   // fp32 div (ref)

    // wave-uniform key band (union over the 16 rows)
    int lo_w = (int)ceilf((float)qi0 * slope - HALF_BW_F);
    if (lo_w < 0) lo_w = 0;
    int hi_w = (int)floorf((float)(qi0 + 15) * slope + HALF_BW_F);
    if (hi_w > key_len - 1) hi_w = key_len - 1;
    const int nt = (hi_w - lo_w) / 16 + 1;           // <= 12

    const int col = lane & 15;             // A: q-row / B: key-within-tile
    const int kg  = lane >> 4;             // K-chunk sub-index

    // ---- Q A-fragments: lane holds Q[qi0+col][kc*32 + kg*8 + 0..7] ----
    const float* qb = Q + ((size_t)b * LQ_ + qi0 + col) * D_ + kg * 8;
    bf16x8 qf[8];
    #pragma unroll
    for (int kc = 0; kc < 8; ++kc) {
        const float4 u = *(const float4*)(qb + kc * 32);
        const float4 v = *(const float4*)(qb + kc * 32 + 4);
        qf[kc] = pack8(u, v);
    }

    // ---- scores: up to 12 key-tiles x 8 chunks of mfma, fp32 accumulate ---
    const float* kb = K + (size_t)b * LK_ * D_ + kg * 8;
    f32x4v acc[NT];
    #pragma unroll
    for (int t = 0; t < NT; ++t) acc[t] = (f32x4v){0.f, 0.f, 0.f, 0.f};

    #pragma unroll
    for (int t = 0; t < NT; ++t) {
        if (t < nt) {                                // wave-uniform guard
            const int key  = lo_w + t * 16 + col;
            const int keyc = (key <= hi_w) ? key : hi_w;   // clamp: in-batch
            const float* kp = kb + (size_t)keyc * D_;
            float4 u[8], w[8];
            #pragma unroll
            for (int kc = 0; kc < 8; ++kc) {
                u[kc] = *(const float4*)(kp + kc * 32);
                w[kc] = *(const float4*)(kp + kc * 32 + 4);
            }
            #pragma unroll
            for (int kc = 0; kc < 8; ++kc) {
                const bf16x8 kf = pack8(u[kc], w[kc]);
                acc[t] = __builtin_amdgcn_mfma_f32_16x16x32_bf16(qf[kc], kf, acc[t], 0, 0, 0);
            }
        }
    }

    // ---- softmax: lane owns rows (kg*4 + r), key col, across nt tiles ----
    // C/D layout [m89-verified]: col=lane&15, row=(lane>>4)*4+reg
    #pragma unroll
    for (int r = 0; r < 4; ++r) {
        const int rg = kg * 4 + r;
        const float center = (float)(qi0 + rg) * slope;
        int klo = (int)ceilf(center - HALF_BW_F); if (klo < 0) klo = 0;
        int khi = (int)floorf(center + HALF_BW_F); if (khi > key_len - 1) khi = key_len - 1;

        float v[NT];
        #pragma unroll
        for (int t = 0; t < NT; ++t) {
            const int key = lo_w + t * 16 + col;
            v[t] = (t < nt && key >= klo && key <= khi) ? acc[t][r] * SCALE : -INFINITY;
        }
        float mx = v[0];
        #pragma unroll
        for (int t = 1; t < NT; ++t) mx = fmaxf(mx, v[t]);
        mx = grp16_max(mx);

        float e[NT], ssum = 0.f;
        #pragma unroll
        for (int t = 0; t < NT; ++t) { e[t] = __expf(v[t] - mx); ssum += e[t]; }
        ssum = grp16_sum(ssum);
        const float inv = 1.0f / ssum;

        #pragma unroll
        for (int t = 0; t < NT; ++t)
            if (t < nt) s_sc[rg][t * 16 + col] = e[t] * inv;  // 0 outside band
    }
    // within-wave LDS write->read is in-order: no barrier needed

    // ---- band stripes (<=2 per row; memset already zeroed the rest) ----
    #pragma unroll
    for (int r = 0; r < 16; ++r) {
        const float center = (float)(qi0 + r) * slope;
        int klo = (int)ceilf(center - HALF_BW_F); if (klo < 0) klo = 0;
        int khi = (int)floorf(center + HALF_BW_F); if (khi > key_len - 1) khi = key_len - 1;
        const int s_lo = klo >> 8, s_hi = khi >> 8;
        float* base = Wout + (size_t)(row0 + r) * LK_;
        const float* sr = &s_sc[r][0];               // indexed by key - lo_w
        for (int j = s_lo; j <= s_hi; ++j) {         // <=2 iterations
            const int c0 = (j * 64 + lane) * 4;
            float w[4] = {0.f, 0.f, 0.f, 0.f};
            if (c0 + 3 >= klo && c0 <= khi) {
                #pragma unroll
                for (int i = 0; i < 4; ++i) {
                    const int c = c0 + i;
                    if (c >= klo && c <= khi) w[i] = sr[c - lo_w];
                }
            }
            float4 w4; w4.x = w[0]; w4.y = w[1]; w4.z = w[2]; w4.w = w[3];
            *(float4*)(base + c0) = w4;
        }
    }
}

extern "C" void kernel_launch(void* const* d_in, const int* in_sizes, int n_in,
                              void* d_out, int out_size, void* d_ws, size_t ws_size,
                              hipStream_t stream) {
    // inputs (setup_inputs order): query, key, value, mask, query_lengths, key_lengths
    const float* Q    = (const float*)d_in[0];
    const float* K    = (const float*)d_in[1];
    const float* V    = (const float*)d_in[2];
    const int*   qlen = (const int*)d_in[4];
    const int*   klen = (const int*)d_in[5];

    float* Wout = (float*)d_out;
    const size_t W_ELEMS = (size_t)B_ * LQ_ * LK_;        // 67,108,864
    float* Vout = Wout + W_ELEMS;
    const size_t W_BYTES = W_ELEMS * sizeof(float);       // 256 MB
    const size_t V_BYTES = (size_t)B_ * LK_ * D_ * sizeof(float);  // 64 MB

    // zeros at the proven ~7 TB/s fillBuffer rate
    hipMemsetAsync(Wout, 0, W_BYTES, stream);
    // V passthrough via the runtime's D2D copy path (~25 us, R1)
    hipMemcpyAsync(Vout, V, V_BYTES, hipMemcpyDeviceToDevice, stream);
    // isolated score phase
    score_kernel<<<dim3(NUNIT), dim3(64), 0, stream>>>(Q, K, qlen, klen, Wout);
}

// Round 20
// 120.327 us; speedup vs baseline: 1.1746x; 1.1746x over previous
//
#include <hip/hip_runtime.h>
#include <math.h>

// Problem constants (from reference)
constexpr int B_  = 16;
constexpr int LQ_ = 1024;
constexpr int LK_ = 4096;
constexpr int D_  = 256;
constexpr float HALF_BW_F = 64.0f;         // 128 // 2
constexpr float SCALE = 0.0625f;           // (D^-0.25)^2 = 1/sqrt(256)

typedef float  fx4    __attribute__((ext_vector_type(4)));
typedef short  bf16x8 __attribute__((ext_vector_type(8)));
typedef float  f32x4v __attribute__((ext_vector_type(4)));

constexpr int ROWS_PER_WAVE = 16;          // one MFMA M-tile per wave-block
constexpr int NUNIT = (B_ * LQ_) / ROWS_PER_WAVE;  // 1024 single-wave blocks
constexpr int NXCD  = 8;
constexpr int UNIT_PER_XCD = NUNIT / NXCD; // 128
constexpr int KSPAN = 192;                 // wave key span <= 15*4+129 = 189
constexpr int NT    = 12;                  // key tiles of 16

__device__ __forceinline__ unsigned short f2bf(float f) {
    unsigned int u = __float_as_uint(f);
    return (unsigned short)((u + 0x7FFFu + ((u >> 16) & 1u)) >> 16);  // RNE
}
__device__ __forceinline__ bf16x8 pack8(float4 a, float4 b) {
    bf16x8 r;
    r[0] = (short)f2bf(a.x); r[1] = (short)f2bf(a.y);
    r[2] = (short)f2bf(a.z); r[3] = (short)f2bf(a.w);
    r[4] = (short)f2bf(b.x); r[5] = (short)f2bf(b.y);
    r[6] = (short)f2bf(b.z); r[7] = (short)f2bf(b.w);
    return r;
}
__device__ __forceinline__ float grp16_max(float v) {
    #pragma unroll
    for (int off = 8; off > 0; off >>= 1)
        v = fmaxf(v, __shfl_xor(v, off, 64));
    return v;
}
__device__ __forceinline__ float grp16_sum(float v) {
    #pragma unroll
    for (int off = 8; off > 0; off >>= 1)
        v += __shfl_xor(v, off, 64);
    return v;
}

// Single-generation fused kernel: 1024 single-wave blocks; each wave does
// MFMA scores (loads FIRST - vmcnt never queues behind stores), softmax,
// then writes its FULL 16 W-rows (zero+band merged, nontemporal) and its
// V slice. R19 decomposition: score phase ~80us isolated, stores proven
// ~9 TB/s with 1024 waves (R13), serialization wastes ~40us vs overlap
// (141 vs 96-102). One generation lets the score-phase stall (unexplained
// 10x over cycle model, survives 10 structural changes) overlap the 380 MB
// store storm instead of preceding it.
__global__ __launch_bounds__(64, 2) void fused_kernel(
    const float* __restrict__ Q, const float* __restrict__ K,
    const float* __restrict__ V,
    const int* __restrict__ qlen, const int* __restrict__ klen,
    float* __restrict__ Wout, float* __restrict__ Vout)
{
    const int Bid  = blockIdx.x;
    // XCD swizzle: each XCD owns 128 consecutive units (2048 rows = 2 batches)
    const int rb   = (Bid & (NXCD - 1)) * UNIT_PER_XCD + (Bid >> 3);
    const int lane = threadIdx.x;          // single wave per block
    const int row0 = rb * ROWS_PER_WAVE;
    const int b    = row0 >> 10;
    const int qi0  = row0 & (LQ_ - 1);

    __shared__ float s_sc[ROWS_PER_WAVE][KSPAN];   // 12 KB

    const int   key_len = klen[b];
    const float slope   = (float)key_len / (float)qlen[b];   // fp32 div (ref)

    // wave-uniform key band (union over the 16 rows)
    int lo_w = (int)ceilf((float)qi0 * slope - HALF_BW_F);
    if (lo_w < 0) lo_w = 0;
    int hi_w = (int)floorf((float)(qi0 + 15) * slope + HALF_BW_F);
    if (hi_w > key_len - 1) hi_w = key_len - 1;
    const int nt = (hi_w - lo_w) / 16 + 1;           // <= 12

    const int col = lane & 15;             // A: q-row / B: key-within-tile
    const int kg  = lane >> 4;             // K-chunk sub-index

    // ---- Q A-fragments: lane holds Q[qi0+col][kc*32 + kg*8 + 0..7] ----
    const float* qb = Q + ((size_t)b * LQ_ + qi0 + col) * D_ + kg * 8;
    bf16x8 qf[8];
    #pragma unroll
    for (int kc = 0; kc < 8; ++kc) {
        const float4 u = *(const float4*)(qb + kc * 32);
        const float4 v = *(const float4*)(qb + kc * 32 + 4);
        qf[kc] = pack8(u, v);
    }

    // ---- scores: up to 12 key-tiles x 8 chunks of mfma, fp32 accumulate ---
    const float* kb = K + (size_t)b * LK_ * D_ + kg * 8;
    f32x4v acc[NT];
    #pragma unroll
    for (int t = 0; t < NT; ++t) acc[t] = (f32x4v){0.f, 0.f, 0.f, 0.f};

    #pragma unroll
    for (int t = 0; t < NT; ++t) {
        if (t < nt) {                                // wave-uniform guard
            const int key  = lo_w + t * 16 + col;
            const int keyc = (key <= hi_w) ? key : hi_w;   // clamp: in-batch
            const float* kp = kb + (size_t)keyc * D_;
            float4 u[8], w[8];
            #pragma unroll
            for (int kc = 0; kc < 8; ++kc) {
                u[kc] = *(const float4*)(kp + kc * 32);
                w[kc] = *(const float4*)(kp + kc * 32 + 4);
            }
            #pragma unroll
            for (int kc = 0; kc < 8; ++kc) {
                const bf16x8 kf = pack8(u[kc], w[kc]);
                acc[t] = __builtin_amdgcn_mfma_f32_16x16x32_bf16(qf[kc], kf, acc[t], 0, 0, 0);
            }
        }
    }

    // ---- softmax: lane owns rows (kg*4 + r), key col, across nt tiles ----
    // C/D layout [m89-verified]: col=lane&15, row=(lane>>4)*4+reg
    #pragma unroll
    for (int r = 0; r < 4; ++r) {
        const int rg = kg * 4 + r;
        const float center = (float)(qi0 + rg) * slope;
        int klo = (int)ceilf(center - HALF_BW_F); if (klo < 0) klo = 0;
        int khi = (int)floorf(center + HALF_BW_F); if (khi > key_len - 1) khi = key_len - 1;

        float v[NT];
        #pragma unroll
        for (int t = 0; t < NT; ++t) {
            const int key = lo_w + t * 16 + col;
            v[t] = (t < nt && key >= klo && key <= khi) ? acc[t][r] * SCALE : -INFINITY;
        }
        float mx = v[0];
        #pragma unroll
        for (int t = 1; t < NT; ++t) mx = fmaxf(mx, v[t]);
        mx = grp16_max(mx);

        float e[NT], ssum = 0.f;
        #pragma unroll
        for (int t = 0; t < NT; ++t) { e[t] = __expf(v[t] - mx); ssum += e[t]; }
        ssum = grp16_sum(ssum);
        const float inv = 1.0f / ssum;

        #pragma unroll
        for (int t = 0; t < NT; ++t)
            if (t < nt) s_sc[rg][t * 16 + col] = e[t] * inv;  // 0 outside band
    }
    // within-wave LDS write->read is in-order: no barrier needed

    // ---- full W rows: zero stripes + band stripes merged (nontemporal) ----
    #pragma unroll
    for (int r = 0; r < 16; ++r) {
        const float center = (float)(qi0 + r) * slope;
        int klo = (int)ceilf(center - HALF_BW_F); if (klo < 0) klo = 0;
        int khi = (int)floorf(center + HALF_BW_F); if (khi > key_len - 1) khi = key_len - 1;
        const int s_lo = klo >> 8, s_hi = khi >> 8;
        float* base = Wout + (size_t)(row0 + r) * LK_;
        const float* sr = &s_sc[r][0];               // indexed by key - lo_w
        #pragma unroll
        for (int j = 0; j < 16; ++j) {
            const int c0 = (j * 64 + lane) * 4;
            float w[4] = {0.f, 0.f, 0.f, 0.f};
            if (j >= s_lo && j <= s_hi && c0 + 3 >= klo && c0 <= khi) {
                #pragma unroll
                for (int i = 0; i < 4; ++i) {
                    const int c = c0 + i;
                    if (c >= klo && c <= khi) w[i] = sr[c - lo_w];
                }
            }
            fx4 w4; w4.x = w[0]; w4.y = w[1]; w4.z = w[2]; w4.w = w[3];
            __builtin_nontemporal_store(w4, (fx4*)(base + c0));
        }
    }

    // ---- V slice: 16 rows = 64 KB (nontemporal copy) ----
    {
        const float* vs = V    + (size_t)row0 * 1024;
        float*       vd = Vout + (size_t)row0 * 1024;
        #pragma unroll
        for (int it = 0; it < 64; ++it) {
            const int o = (it * 64 + lane) * 4;
            fx4 t = __builtin_nontemporal_load((const fx4*)(vs + o));
            __builtin_nontemporal_store(t, (fx4*)(vd + o));
        }
    }
}

extern "C" void kernel_launch(void* const* d_in, const int* in_sizes, int n_in,
                              void* d_out, int out_size, void* d_ws, size_t ws_size,
                              hipStream_t stream) {
    // inputs (setup_inputs order): query, key, value, mask, query_lengths, key_lengths
    const float* Q    = (const float*)d_in[0];
    const float* K    = (const float*)d_in[1];
    const float* V    = (const float*)d_in[2];
    const int*   qlen = (const int*)d_in[4];
    const int*   klen = (const int*)d_in[5];

    float* Wout = (float*)d_out;
    const size_t W_ELEMS = (size_t)B_ * LQ_ * LK_;        // 67,108,864
    float* Vout = Wout + W_ELEMS;

    fused_kernel<<<dim3(NUNIT), dim3(64), 0, stream>>>(
        Q, K, V, qlen, klen, Wout, Vout);
}

// Round 21
// 99.199 us; speedup vs baseline: 1.4247x; 1.2130x over previous
//
#include <hip/hip_runtime.h>
#include <math.h>

// Problem constants (from reference)
constexpr int B_  = 16;
constexpr int LQ_ = 1024;
constexpr int LK_ = 4096;
constexpr int D_  = 256;
constexpr float HALF_BW_F = 64.0f;         // 128 // 2
constexpr float SCALE = 0.0625f;           // (D^-0.25)^2 = 1/sqrt(256)

typedef float  fx4    __attribute__((ext_vector_type(4)));
typedef short  bf16x8 __attribute__((ext_vector_type(8)));
typedef float  f32x4v __attribute__((ext_vector_type(4)));

constexpr int ROWS_PER_UNIT = 16;          // one MFMA M-tile per block
constexpr int NUNIT = (B_ * LQ_) / ROWS_PER_UNIT;  // 1024 blocks
constexpr int NXCD  = 8;
constexpr int UNIT_PER_XCD = NUNIT / NXCD; // 128
constexpr int KSPAN = 192;                 // unit key span <= 15*4+129 = 189
constexpr int NT    = 12;                  // key tiles of 16
constexpr int TPW   = 3;                   // tiles per wave (12 / 4 waves)

__device__ __forceinline__ unsigned short f2bf(float f) {
    unsigned int u = __float_as_uint(f);
    return (unsigned short)((u + 0x7FFFu + ((u >> 16) & 1u)) >> 16);  // RNE
}
__device__ __forceinline__ bf16x8 pack8(float4 a, float4 b) {
    bf16x8 r;
    r[0] = (short)f2bf(a.x); r[1] = (short)f2bf(a.y);
    r[2] = (short)f2bf(a.z); r[3] = (short)f2bf(a.w);
    r[4] = (short)f2bf(b.x); r[5] = (short)f2bf(b.y);
    r[6] = (short)f2bf(b.z); r[7] = (short)f2bf(b.w);
    return r;
}
__device__ __forceinline__ float wave_max(float v) {
    #pragma unroll
    for (int off = 32; off > 0; off >>= 1)
        v = fmaxf(v, __shfl_xor(v, off, 64));
    return v;
}
__device__ __forceinline__ float wave_sum(float v) {
    #pragma unroll
    for (int off = 32; off > 0; off >>= 1)
        v += __shfl_xor(v, off, 64);
    return v;
}

// Cooperative 4-wave MFMA kernel. R20 post-mortem: single-wave blocks ran
// the score phase at 1 wave/SIMD (zero latency hiding) AND pumped 380 MB
// of stores at 4 waves/CU. Now: block = 4 waves owns one 16-row unit;
// the <=12 key-tiles are dealt round-robin (wave w: tiles w, w+4, w+8 ->
// serial chain /4), raw scores meet in LDS (one barrier), then wave w
// softmaxes AND stores rows w*4..w*4+3 (no 2nd barrier: same-wave LDS
// write->read is in-order). 4096 waves total = 16/CU for the store storm.
__global__ __launch_bounds__(256, 4) void fused_kernel(
    const float* __restrict__ Q, const float* __restrict__ K,
    const float* __restrict__ V,
    const int* __restrict__ qlen, const int* __restrict__ klen,
    float* __restrict__ Wout, float* __restrict__ Vout)
{
    const int Bid  = blockIdx.x;
    // XCD swizzle: each XCD owns 128 consecutive units (2048 rows = 2 batches)
    const int unit = (Bid & (NXCD - 1)) * UNIT_PER_XCD + (Bid >> 3);
    const int tid  = threadIdx.x;
    const int lane = tid & 63;
    const int wave = tid >> 6;
    const int row0 = unit * ROWS_PER_UNIT;
    const int b    = row0 >> 10;
    const int qi0  = row0 & (LQ_ - 1);

    __shared__ float s_sc[ROWS_PER_UNIT][KSPAN];   // 12 KB

    const int   key_len = klen[b];
    const float slope   = (float)key_len / (float)qlen[b];   // fp32 div (ref)

    // unit-uniform key band (union over the 16 rows)
    int lo_w = (int)ceilf((float)qi0 * slope - HALF_BW_F);
    if (lo_w < 0) lo_w = 0;
    int hi_w = (int)floorf((float)(qi0 + 15) * slope + HALF_BW_F);
    if (hi_w > key_len - 1) hi_w = key_len - 1;
    const int nt = (hi_w - lo_w) / 16 + 1;           // <= 12

    const int col = lane & 15;             // A: q-row / B: key-within-tile
    const int kg  = lane >> 4;             // K-chunk sub-index

    // ---- Q A-fragments: lane holds Q[qi0+col][kc*32 + kg*8 + 0..7] ----
    const float* qb = Q + ((size_t)b * LQ_ + qi0 + col) * D_ + kg * 8;
    bf16x8 qf[8];
    #pragma unroll
    for (int kc = 0; kc < 8; ++kc) {
        const float4 u = *(const float4*)(qb + kc * 32);
        const float4 v = *(const float4*)(qb + kc * 32 + 4);
        qf[kc] = pack8(u, v);
    }

    // ---- scores: this wave's tiles t = wave + 4*s, s = 0..2 ----
    const float* kb = K + (size_t)b * LK_ * D_ + kg * 8;
    #pragma unroll
    for (int s = 0; s < TPW; ++s) {
        const int t = wave + 4 * s;
        if (t < nt) {                                // wave-uniform guard
            const int key  = lo_w + t * 16 + col;
            const int keyc = (key <= hi_w) ? key : hi_w;   // clamp: in-batch
            const float* kp = kb + (size_t)keyc * D_;
            float4 u[8], w[8];
            #pragma unroll
            for (int kc = 0; kc < 8; ++kc) {
                u[kc] = *(const float4*)(kp + kc * 32);
                w[kc] = *(const float4*)(kp + kc * 32 + 4);
            }
            f32x4v acc = (f32x4v){0.f, 0.f, 0.f, 0.f};
            #pragma unroll
            for (int kc = 0; kc < 8; ++kc) {
                const bf16x8 kf = pack8(u[kc], w[kc]);
                acc = __builtin_amdgcn_mfma_f32_16x16x32_bf16(qf[kc], kf, acc, 0, 0, 0);
            }
            // C/D layout [m89]: col=lane&15, row=(lane>>4)*4+reg
            #pragma unroll
            for (int r = 0; r < 4; ++r)
                s_sc[kg * 4 + r][t * 16 + col] = acc[r] * SCALE;
        }
    }
    __syncthreads();   // all tiles' raw scores visible to all waves

    // ---- softmax + stores: wave owns rows wave*4 .. wave*4+3 ----
    #pragma unroll
    for (int r = 0; r < 4; ++r) {
        const int rg = wave * 4 + r;
        const float center = (float)(qi0 + rg) * slope;
        int klo = (int)ceilf(center - HALF_BW_F); if (klo < 0) klo = 0;
        int khi = (int)floorf(center + HALF_BW_F); if (khi > key_len - 1) khi = key_len - 1;

        // 3 values/lane over the 192-slot union span, masked by row band
        float v0, v1, v2;
        {
            const int i0 = lane, i1 = lane + 64, i2 = lane + 128;
            const int c0 = lo_w + i0, c1 = lo_w + i1, c2 = lo_w + i2;
            v0 = (c0 >= klo && c0 <= khi) ? s_sc[rg][i0] : -INFINITY;
            v1 = (c1 >= klo && c1 <= khi) ? s_sc[rg][i1] : -INFINITY;
            v2 = (c2 >= klo && c2 <= khi) ? s_sc[rg][i2] : -INFINITY;
        }
        const float mx = wave_max(fmaxf(fmaxf(v0, v1), v2));
        const float e0 = __expf(v0 - mx);   // exp(-inf)=0 for masked slots
        const float e1 = __expf(v1 - mx);
        const float e2 = __expf(v2 - mx);
        const float ssum = wave_sum(e0 + e1 + e2);
        const float inv = 1.0f / ssum;
        s_sc[rg][lane]       = e0 * inv;    // masked slots become 0
        s_sc[rg][lane + 64]  = e1 * inv;
        s_sc[rg][lane + 128] = e2 * inv;
        // same-wave LDS write->read is in-order: store directly

        const int s_lo = klo >> 8, s_hi = khi >> 8;
        float* base = Wout + (size_t)(row0 + rg) * LK_;
        const float* sr = &s_sc[rg][0];              // indexed by key - lo_w
        #pragma unroll
        for (int j = 0; j < 16; ++j) {
            const int c0 = (j * 64 + lane) * 4;
            float w[4] = {0.f, 0.f, 0.f, 0.f};
            if (j >= s_lo && j <= s_hi && c0 + 3 >= klo && c0 <= khi) {
                #pragma unroll
                for (int i = 0; i < 4; ++i) {
                    const int c = c0 + i;
                    if (c >= klo && c <= khi) w[i] = sr[c - lo_w];
                }
            }
            fx4 w4; w4.x = w[0]; w4.y = w[1]; w4.z = w[2]; w4.w = w[3];
            __builtin_nontemporal_store(w4, (fx4*)(base + c0));
        }
    }

    // ---- V slice: wave copies its 4 rows (16 KB, nontemporal) ----
    {
        const float* vs = V    + (size_t)(row0 + wave * 4) * 1024;
        float*       vd = Vout + (size_t)(row0 + wave * 4) * 1024;
        #pragma unroll
        for (int it = 0; it < 16; ++it) {
            const int o = (it * 64 + lane) * 4;
            fx4 t = __builtin_nontemporal_load((const fx4*)(vs + o));
            __builtin_nontemporal_store(t, (fx4*)(vd + o));
        }
    }
}

extern "C" void kernel_launch(void* const* d_in, const int* in_sizes, int n_in,
                              void* d_out, int out_size, void* d_ws, size_t ws_size,
                              hipStream_t stream) {
    // inputs (setup_inputs order): query, key, value, mask, query_lengths, key_lengths
    const float* Q    = (const float*)d_in[0];
    const float* K    = (const float*)d_in[1];
    const float* V    = (const float*)d_in[2];
    const int*   qlen = (const int*)d_in[4];
    const int*   klen = (const int*)d_in[5];

    float* Wout = (float*)d_out;
    const size_t W_ELEMS = (size_t)B_ * LQ_ * LK_;        // 67,108,864
    float* Vout = Wout + W_ELEMS;

    fused_kernel<<<dim3(NUNIT), dim3(256), 0, stream>>>(
        Q, K, V, qlen, klen, Wout, Vout);
}